// Round 2
// baseline (181.914 us; speedup 1.0000x reference)
//
#include <hip/hip_runtime.h>
#include <hip/hip_bf16.h>

typedef __bf16 bf16x8 __attribute__((ext_vector_type(8)));
typedef short  s16x4  __attribute__((ext_vector_type(4)));
typedef float  f32x4  __attribute__((ext_vector_type(4)));
typedef unsigned short u16x8 __attribute__((ext_vector_type(8)));
typedef unsigned short u16x4 __attribute__((ext_vector_type(4)));

// ---------- helpers ----------

__device__ __forceinline__ unsigned short f2bf(float f) {
  return __builtin_bit_cast(unsigned short, (__bf16)f);  // RNE via v_cvt
}

__device__ __forceinline__ bf16x8 ld8(const unsigned short* p) {
  return __builtin_bit_cast(bf16x8, *reinterpret_cast<const u16x8*>(p));
}

// async global->LDS, 16B per lane. lds must be wave-uniform (HW adds lane*16).
__device__ __forceinline__ void gload16(const unsigned short* src, unsigned short* lds) {
  __builtin_amdgcn_global_load_lds(
      (const __attribute__((address_space(1))) unsigned int*)src,
      (__attribute__((address_space(3))) unsigned int*)lds,
      16, 0, 0);
}

// ---------- GEMM: C[m,n] = sum_k A[m,k] * W[n,k]  (NT, f32 in, bf16 MFMA, f32 acc) ----------
// M=4096, N=1024, K=1024. 128x128 tile, BK=32, 256 threads (2x2 waves of 64x64).
// A, W are float32; converted to bf16 at staging (inputs are bf16-representable).
// mode 0: C float32 row-major (M x 1024)
// mode 1: C bf16 -> qk layout  [(b*16+h)*2048 + s]*64 + d
// mode 2: C bf16 -> v-transposed [(b*16+h)*64 + d]*2048 + s

__device__ __forceinline__ void gemm_body(const float* __restrict__ A,
                                          const float* __restrict__ W,
                                          void* __restrict__ Cv, int mode) {
  __shared__ unsigned short As[2][128 * 32];
  __shared__ unsigned short Bs[2][128 * 32];
  const int tid  = threadIdx.x;
  const int lane = tid & 63;
  const int g    = lane >> 4;
  const int lo   = lane & 15;
  const int wid  = tid >> 6;
  const int m0   = blockIdx.y * 128;
  const int n0   = blockIdx.x * 128;
  const int wm   = wid >> 1, wn = wid & 1;

  f32x4 acc[4][4] = {};

  auto stage_issue = [&](int k0, f32x4* ar, f32x4* wr) {
#pragma unroll
    for (int i = 0; i < 4; ++i) {
      const int c = i * 256 + tid;            // 1024 chunks of 4 floats
      const int row = c >> 3, cc = c & 7;     // 8 chunks per 32-float row
      ar[i] = *reinterpret_cast<const f32x4*>(A + (size_t)(m0 + row) * 1024 + k0 + cc * 4);
      wr[i] = *reinterpret_cast<const f32x4*>(W + (size_t)(n0 + row) * 1024 + k0 + cc * 4);
    }
  };
  auto stage_write = [&](int buf, const f32x4* ar, const f32x4* wr) {
#pragma unroll
    for (int i = 0; i < 4; ++i) {
      const int c = i * 256 + tid;
      const int row = c >> 3, cc = c & 7;
      u16x4 ha, hw;
#pragma unroll
      for (int j = 0; j < 4; ++j) { ha[j] = f2bf(ar[i][j]); hw[j] = f2bf(wr[i][j]); }
      *reinterpret_cast<u16x4*>(&As[buf][row * 32 + cc * 4]) = ha;
      *reinterpret_cast<u16x4*>(&Bs[buf][row * 32 + cc * 4]) = hw;
    }
  };

  {
    f32x4 ar[4], wr[4];
    stage_issue(0, ar, wr);
    stage_write(0, ar, wr);
  }
  __syncthreads();

  int cur = 0;
  for (int t = 0; t < 32; ++t) {
    f32x4 ar[4], wr[4];
    if (t < 31) stage_issue((t + 1) * 32, ar, wr);   // issue early, hide under MFMA

    bf16x8 af[4], bvf[4];
#pragma unroll
    for (int mi = 0; mi < 4; ++mi)
      af[mi] = ld8(&As[cur][(wm * 64 + mi * 16 + lo) * 32 + g * 8]);
#pragma unroll
    for (int ni = 0; ni < 4; ++ni)
      bvf[ni] = ld8(&Bs[cur][(wn * 64 + ni * 16 + lo) * 32 + g * 8]);
#pragma unroll
    for (int mi = 0; mi < 4; ++mi)
#pragma unroll
      for (int ni = 0; ni < 4; ++ni)
        acc[mi][ni] = __builtin_amdgcn_mfma_f32_16x16x32_bf16(af[mi], bvf[ni], acc[mi][ni], 0, 0, 0);

    if (t < 31) stage_write(cur ^ 1, ar, wr);        // buf[cur^1] last read at t-1, safe
    __syncthreads();
    cur ^= 1;
  }

  // epilogue: C/D layout col = lane&15 (n), row = g*4 + r (m)
#pragma unroll
  for (int mi = 0; mi < 4; ++mi) {
#pragma unroll
    for (int ni = 0; ni < 4; ++ni) {
      const int gcol = n0 + wn * 64 + ni * 16 + lo;
#pragma unroll
      for (int r = 0; r < 4; ++r) {
        const int grow = m0 + wm * 64 + mi * 16 + g * 4 + r;
        if (mode == 0) {
          ((float*)Cv)[(size_t)grow * 1024 + gcol] = acc[mi][ni][r];
        } else {
          const unsigned short bv = f2bf(acc[mi][ni][r]);
          const int b = grow >> 11, s = grow & 2047;
          const int h = gcol >> 6, d = gcol & 63;
          if (mode == 1) ((unsigned short*)Cv)[(((size_t)(b * 16 + h)) * 2048 + s) * 64 + d] = bv;
          else           ((unsigned short*)Cv)[(((size_t)(b * 16 + h)) * 64 + d) * 2048 + s] = bv;
        }
      }
    }
  }
}

__global__ __launch_bounds__(256) void gemm_qkv(
    const float* __restrict__ x,
    const float* __restrict__ Wq,
    const float* __restrict__ Wk,
    const float* __restrict__ Wv,
    unsigned short* __restrict__ q_s,
    unsigned short* __restrict__ k_s,
    unsigned short* __restrict__ vt_s) {
  const float* W;
  void* o;
  int mode;
  if (blockIdx.z == 0)      { W = Wq; o = q_s;  mode = 1; }
  else if (blockIdx.z == 1) { W = Wk; o = k_s;  mode = 1; }
  else                      { W = Wv; o = vt_s; mode = 2; }
  gemm_body(x, W, o, mode);
}

__global__ __launch_bounds__(256) void gemm_out(
    const float* __restrict__ a_s,
    const float* __restrict__ Wo,
    float* __restrict__ out) {
  gemm_body(a_s, Wo, out, 0);
}

// ---------- flash attention (causal) ----------
// Q,K: (b,h,s,64) bf16 ; Vt: (b,h,64,s) bf16 ; O: (b,s,1024) float32
// grid: (32 q-tiles, 32 bh). 256 threads = 4 waves, wave owns 16 q rows.
// Swapped QK^T: S^T = mfma(K, Q) -> lane's q = lane&15 for both S and O.

__global__ __launch_bounds__(256) void attn_fwd(
    const unsigned short* __restrict__ Q,
    const unsigned short* __restrict__ K,
    const unsigned short* __restrict__ Vt,
    float* __restrict__ O) {
  __shared__ unsigned short Kl[2][64 * 64];   // [key][d], chunk-swizzled
  __shared__ unsigned short Vl[2][64 * 64];   // [d][s],   chunk-swizzled
  const int tid  = threadIdx.x;
  const int lane = tid & 63;
  const int wid  = tid >> 6;
  const int g    = lane >> 4;
  const int lo   = lane & 15;
  const int bh   = blockIdx.y;
  const int qt   = (int)gridDim.x - 1 - (int)blockIdx.x;  // longest blocks first
  const int q0   = qt * 64;
  const int qw0  = q0 + wid * 16;

  const unsigned short* Qb = Q  + (size_t)bh * 2048 * 64;
  const unsigned short* Kb = K  + (size_t)bh * 2048 * 64;
  const unsigned short* Vb = Vt + (size_t)bh * 64 * 2048;

  // Q fragments (B operand of swapped QK^T): col q = lane&15, k = d = g*8+j
  bf16x8 qf[2];
#pragma unroll
  for (int ks = 0; ks < 2; ++ks)
    qf[ks] = ld8(Qb + (size_t)(qw0 + lo) * 64 + ks * 32 + g * 8);

  f32x4 oacc[4] = {};
  float m = -INFINITY, l = 0.f;
  const float SC = 0.125f * 1.4426950408889634f;  // scale * log2(e), softmax in exp2 domain
  const int nt = qt + 1;

  auto stage = [&](int buf, int t) {
    const int k0 = t * 64;
#pragma unroll
    for (int i = 0; i < 2; ++i) {
      const int c   = (i * 4 + wid) * 64 + lane;
      const int row = c >> 3, cc = c & 7;          // 8 chunks per 128B row
      const int scc = cc ^ (row & 7);              // pre-swizzled source (m173)
      gload16(Kb + (size_t)(k0 + row) * 64 + scc * 8, &Kl[buf][(i * 4 + wid) * 512]);
      gload16(Vb + (size_t)row * 2048 + k0 + scc * 8, &Vl[buf][(i * 4 + wid) * 512]);
    }
  };

  stage(0, 0);
  __syncthreads();
  int cur = 0;

  for (int t = 0; t < nt; ++t) {
    if (t + 1 < nt) stage(cur ^ 1, t + 1);

    // S^T[key][q], 4 key-tiles of 16
    f32x4 sv[4];
#pragma unroll
    for (int kt = 0; kt < 4; ++kt) {
      f32x4 a = {};
#pragma unroll
      for (int ks = 0; ks < 2; ++ks) {
        const int key = kt * 16 + lo;
        const int ck  = ks * 4 + g;
        bf16x8 kf = ld8(&Kl[cur][key * 64 + (ck ^ (key & 7)) * 8]);
        a = __builtin_amdgcn_mfma_f32_16x16x32_bf16(kf, qf[ks], a, 0, 0, 0);
      }
      sv[kt] = a;
    }

    // scale + causal mask (lane's q = qw0+lo; lane's keys = t*64 + kt*16 + g*4 + r)
    const bool lastt = (t == nt - 1);
    float tmax = -INFINITY;
#pragma unroll
    for (int kt = 0; kt < 4; ++kt)
#pragma unroll
      for (int r = 0; r < 4; ++r) {
        float v = sv[kt][r] * SC;
        if (lastt) {
          const int key = t * 64 + kt * 16 + g * 4 + r;
          if (key > qw0 + lo) v = -INFINITY;
        }
        sv[kt][r] = v;
        tmax = fmaxf(tmax, v);
      }
    tmax = fmaxf(tmax, __shfl_xor(tmax, 16));
    tmax = fmaxf(tmax, __shfl_xor(tmax, 32));
    const float mn   = fmaxf(m, tmax);
    const float corr = exp2f(m - mn);
    l *= corr;
#pragma unroll
    for (int dt = 0; dt < 4; ++dt)
#pragma unroll
      for (int r = 0; r < 4; ++r) oacc[dt][r] *= corr;

    float ps = 0.f;
    s16x4 pb[4];
#pragma unroll
    for (int kt = 0; kt < 4; ++kt)
#pragma unroll
      for (int r = 0; r < 4; ++r) {
        const float p = exp2f(sv[kt][r] - mn);
        ps += p;
        pb[kt][r] = (short)f2bf(p);
      }
    ps += __shfl_xor(ps, 16);
    ps += __shfl_xor(ps, 32);
    l += ps;
    m = mn;

    // PV: O^T[d][q] += sum_key Vt[d][key] * P^T[key][q]  (16x16x16, k = g*4+j)
#pragma unroll
    for (int dt = 0; dt < 4; ++dt) {
      const int dl = dt * 16 + lo;
#pragma unroll
      for (int kt = 0; kt < 4; ++kt) {
        const int ck  = 2 * kt + (g >> 1);
        const int off = dl * 64 + ((ck ^ (dl & 7)) * 8) + (g & 1) * 4;
        s16x4 vf = *reinterpret_cast<const s16x4*>(&Vl[cur][off]);
        oacc[dt] = __builtin_amdgcn_mfma_f32_16x16x16bf16_1k(vf, pb[kt], oacc[dt], 0, 0, 0);
      }
    }

    __syncthreads();
    cur ^= 1;
  }

  // epilogue: lane's q = qw0+lo; oacc[dt] rows = d = dt*16 + g*4 + r
  const float inv = 1.f / l;
  const int b = bh >> 4, h = bh & 15;
  const int s = qw0 + lo;
#pragma unroll
  for (int dt = 0; dt < 4; ++dt) {
    f32x4 pk;
#pragma unroll
    for (int r = 0; r < 4; ++r) pk[r] = oacc[dt][r] * inv;
    *reinterpret_cast<f32x4*>(&O[((size_t)(b * 2048 + s)) * 1024 + h * 64 + dt * 16 + g * 4]) = pk;
  }
}

// ---------- launch ----------

extern "C" void kernel_launch(void* const* d_in, const int* in_sizes, int n_in,
                              void* d_out, int out_size, void* d_ws, size_t ws_size,
                              hipStream_t stream) {
  const float* x  = (const float*)d_in[0];
  const float* Wq = (const float*)d_in[1];
  const float* Wk = (const float*)d_in[2];
  const float* Wv = (const float*)d_in[3];
  const float* Wo = (const float*)d_in[4];
  float* out = (float*)d_out;

  char* ws = (char*)d_ws;
  unsigned short* q_s  = (unsigned short*)(ws);                              // 8 MB bf16
  unsigned short* k_s  = (unsigned short*)(ws + (size_t)8  * 1024 * 1024);   // 8 MB bf16
  unsigned short* vt_s = (unsigned short*)(ws + (size_t)16 * 1024 * 1024);   // 8 MB bf16
  float*          a_s  = (float*)         (ws + (size_t)24 * 1024 * 1024);   // 16 MB f32

  dim3 blk(256);
  gemm_qkv<<<dim3(8, 32, 3), blk, 0, stream>>>(x, Wq, Wk, Wv, q_s, k_s, vt_s);
  attn_fwd<<<dim3(32, 32, 1), blk, 0, stream>>>(q_s, k_s, vt_s, a_s);
  gemm_out<<<dim3(8, 32, 1), blk, 0, stream>>>(a_s, Wo, out);
}

// Round 3
// 141.287 us; speedup vs baseline: 1.2875x; 1.2875x over previous
//
#include <hip/hip_runtime.h>
#include <hip/hip_bf16.h>

typedef __bf16 bf16x8 __attribute__((ext_vector_type(8)));
typedef short  s16x4  __attribute__((ext_vector_type(4)));
typedef float  f32x4  __attribute__((ext_vector_type(4)));
typedef unsigned short u16x8 __attribute__((ext_vector_type(8)));
typedef unsigned short u16x4 __attribute__((ext_vector_type(4)));

// ---------- helpers ----------

__device__ __forceinline__ unsigned short f2bf(float f) {
  return __builtin_bit_cast(unsigned short, (__bf16)f);  // RNE via v_cvt
}

__device__ __forceinline__ bf16x8 ld8(const unsigned short* p) {
  return __builtin_bit_cast(bf16x8, *reinterpret_cast<const u16x8*>(p));
}

// async global->LDS, 16B per lane. lds base must be wave-uniform (HW adds lane*16).
__device__ __forceinline__ void gload16(const unsigned short* src, unsigned short* lds) {
  __builtin_amdgcn_global_load_lds(
      (const __attribute__((address_space(1))) unsigned int*)src,
      (__attribute__((address_space(3))) unsigned int*)lds,
      16, 0, 0);
}

// ---------- input conversion: f32 -> bf16 ----------
// x: 4,194,304 elems; Wq/Wk/Wv/Wo: 1,048,576 each (contiguous in wb).

__global__ __launch_bounds__(256) void cvt_inputs(
    const float* __restrict__ x, const float* __restrict__ Wq,
    const float* __restrict__ Wk, const float* __restrict__ Wv,
    const float* __restrict__ Wo,
    unsigned short* __restrict__ xb, unsigned short* __restrict__ wb) {
  const int NXC = 4194304 / 8;
  const int NWC = 1048576 / 8;   // 131072 = 2^17
  const int total = NXC + 4 * NWC;
  for (int cid = blockIdx.x * 256 + threadIdx.x; cid < total; cid += gridDim.x * 256) {
    const float* s; unsigned short* d; int off;
    if (cid < NXC) { s = x; d = xb; off = cid * 8; }
    else {
      const int c2 = cid - NXC; const int w = c2 >> 17; const int o2 = c2 & (NWC - 1);
      s = (w == 0) ? Wq : (w == 1) ? Wk : (w == 2) ? Wv : Wo;
      d = wb + (size_t)w * 1048576;
      off = o2 * 8;
    }
    const f32x4 a  = *reinterpret_cast<const f32x4*>(s + off);
    const f32x4 b2 = *reinterpret_cast<const f32x4*>(s + off + 4);
    u16x8 o;
#pragma unroll
    for (int j = 0; j < 4; ++j) { o[j] = f2bf(a[j]); o[j + 4] = f2bf(b2[j]); }
    *reinterpret_cast<u16x8*>(d + off) = o;
  }
}

// ---------- GEMM: C[m,n] = sum_k A[m,k] * W[n,k]  (NT, bf16 in, f32 acc) ----------
// M=4096, N=1024, K=1024. 128x128 tile, BK=32, 256 threads (2x2 waves of 64x64).
// mode 0: C float32 row-major (M x 1024)
// mode 1: C bf16 -> qk layout  [(b*16+h)*2048 + s]*64 + d
// mode 2: C bf16 -> v-transposed [(b*16+h)*64 + d]*2048 + s

__device__ __forceinline__ void gemm_body(const unsigned short* __restrict__ A,
                                          const unsigned short* __restrict__ W,
                                          void* __restrict__ Cv, int mode) {
  __shared__ unsigned short As[2][128 * 32];
  __shared__ unsigned short Bs[2][128 * 32];
  const int tid  = threadIdx.x;
  const int lane = tid & 63;
  const int g    = lane >> 4;
  const int lo   = lane & 15;
  const int wid  = tid >> 6;
  const int m0   = blockIdx.y * 128;
  const int n0   = blockIdx.x * 128;
  const int wm   = wid >> 1, wn = wid & 1;

  f32x4 acc[4][4] = {};

  auto stage = [&](int buf, int k0) {
#pragma unroll
    for (int i = 0; i < 2; ++i) {
      const int c   = (i * 4 + wid) * 64 + lane;   // 16B chunk id, 512 total
      const int row = c >> 2, cc = c & 3;          // 4 chunks per 64B row (BK=32)
      gload16(A + (size_t)(m0 + row) * 1024 + k0 + cc * 8, &As[buf][(i * 4 + wid) * 512]);
      gload16(W + (size_t)(n0 + row) * 1024 + k0 + cc * 8, &Bs[buf][(i * 4 + wid) * 512]);
    }
  };

  stage(0, 0);
  __syncthreads();
  int cur = 0;
  for (int t = 0; t < 32; ++t) {
    if (t < 31) stage(cur ^ 1, (t + 1) * 32);
    bf16x8 af[4], bvf[4];
#pragma unroll
    for (int mi = 0; mi < 4; ++mi)
      af[mi] = ld8(&As[cur][(wm * 64 + mi * 16 + lo) * 32 + g * 8]);
#pragma unroll
    for (int ni = 0; ni < 4; ++ni)
      bvf[ni] = ld8(&Bs[cur][(wn * 64 + ni * 16 + lo) * 32 + g * 8]);
#pragma unroll
    for (int mi = 0; mi < 4; ++mi)
#pragma unroll
      for (int ni = 0; ni < 4; ++ni)
        acc[mi][ni] = __builtin_amdgcn_mfma_f32_16x16x32_bf16(af[mi], bvf[ni], acc[mi][ni], 0, 0, 0);
    __syncthreads();
    cur ^= 1;
  }

  // epilogue: C/D layout col = lane&15 (n), row = g*4 + r (m)
#pragma unroll
  for (int mi = 0; mi < 4; ++mi) {
#pragma unroll
    for (int ni = 0; ni < 4; ++ni) {
      const int gcol = n0 + wn * 64 + ni * 16 + lo;
#pragma unroll
      for (int r = 0; r < 4; ++r) {
        const int grow = m0 + wm * 64 + mi * 16 + g * 4 + r;
        if (mode == 0) {
          ((float*)Cv)[(size_t)grow * 1024 + gcol] = acc[mi][ni][r];
        } else {
          const unsigned short bv = f2bf(acc[mi][ni][r]);
          const int b = grow >> 11, s = grow & 2047;
          const int h = gcol >> 6, d = gcol & 63;
          if (mode == 1) ((unsigned short*)Cv)[(((size_t)(b * 16 + h)) * 2048 + s) * 64 + d] = bv;
          else           ((unsigned short*)Cv)[(((size_t)(b * 16 + h)) * 64 + d) * 2048 + s] = bv;
        }
      }
    }
  }
}

__global__ __launch_bounds__(256) void gemm_qkv(
    const unsigned short* __restrict__ xb,
    const unsigned short* __restrict__ wb,
    unsigned short* __restrict__ q_s,
    unsigned short* __restrict__ k_s,
    unsigned short* __restrict__ vt_s) {
  const unsigned short* W = wb + (size_t)blockIdx.z * 1048576;
  void* o; int mode;
  if (blockIdx.z == 0)      { o = q_s;  mode = 1; }
  else if (blockIdx.z == 1) { o = k_s;  mode = 1; }
  else                      { o = vt_s; mode = 2; }
  gemm_body(xb, W, o, mode);
}

__global__ __launch_bounds__(256) void gemm_out(
    const unsigned short* __restrict__ a_s,
    const unsigned short* __restrict__ wb,
    float* __restrict__ out) {
  gemm_body(a_s, wb + (size_t)3 * 1048576, out, 0);
}

// ---------- flash attention (causal, paired q-tiles) ----------
// Q,K: (b,h,s,64) bf16 ; Vt: (b,h,64,s) bf16 ; O: (b,s,1024) bf16
// grid: (16 pairs, 32 bh). Block i does q-tiles {31-i, i} -> uniform 33 KV tiles.
// 256 threads = 4 waves, wave owns 16 q rows. Swapped QK^T: S^T = mfma(K, Q).

__global__ __launch_bounds__(256) void attn_fwd(
    const unsigned short* __restrict__ Q,
    const unsigned short* __restrict__ K,
    const unsigned short* __restrict__ Vt,
    unsigned short* __restrict__ O) {
  __shared__ unsigned short Kl[2][64 * 64];   // [key][d], chunk-swizzled
  __shared__ unsigned short Vl[2][64 * 64];   // [d][s],   chunk-swizzled
  const int tid  = threadIdx.x;
  const int lane = tid & 63;
  const int wid  = tid >> 6;
  const int g    = lane >> 4;
  const int lo   = lane & 15;
  const int bh   = blockIdx.y;
  const int b    = bh >> 4, h = bh & 15;

  const unsigned short* Qb = Q  + (size_t)bh * 2048 * 64;
  const unsigned short* Kb = K  + (size_t)bh * 2048 * 64;
  const unsigned short* Vb = Vt + (size_t)bh * 64 * 2048;
  const float SC = 0.125f * 1.4426950408889634f;  // scale * log2(e): exp2 domain

  auto stage = [&](int buf, int t) {
    const int k0 = t * 64;
#pragma unroll
    for (int i = 0; i < 2; ++i) {
      const int c   = (i * 4 + wid) * 64 + lane;
      const int row = c >> 3, cc = c & 7;          // 8 chunks per 128B row
      const int scc = cc ^ (row & 7);              // pre-swizzled source (m173)
      gload16(Kb + (size_t)(t * 64 + row) * 64 + scc * 8, &Kl[buf][(i * 4 + wid) * 512]);
      gload16(Vb + (size_t)row * 2048 + k0 + scc * 8, &Vl[buf][(i * 4 + wid) * 512]);
    }
  };

  auto run = [&](int qt) {
    const int qw0 = qt * 64 + wid * 16;
    // Q fragments (B operand of swapped QK^T), pre-scaled by SC
    bf16x8 qf[2];
#pragma unroll
    for (int ks = 0; ks < 2; ++ks) {
      bf16x8 tq = ld8(Qb + (size_t)(qw0 + lo) * 64 + ks * 32 + g * 8);
#pragma unroll
      for (int j = 0; j < 8; ++j) tq[j] = (__bf16)((float)tq[j] * SC);
      qf[ks] = tq;
    }

    f32x4 oacc[4] = {};
    float m = -INFINITY, l = 0.f;
    const int nt = qt + 1;

    stage(0, 0);
    __syncthreads();
    int cur = 0;

    for (int t = 0; t < nt; ++t) {
      if (t + 1 < nt) stage(cur ^ 1, t + 1);

      // S^T[key][q], 4 key-tiles of 16 (already scaled via Q)
      f32x4 sv[4];
      __builtin_amdgcn_s_setprio(1);
#pragma unroll
      for (int kt = 0; kt < 4; ++kt) {
        f32x4 a = {};
#pragma unroll
        for (int ks = 0; ks < 2; ++ks) {
          const int key = kt * 16 + lo;
          const int ck  = ks * 4 + g;
          bf16x8 kf = ld8(&Kl[cur][key * 64 + (ck ^ (key & 7)) * 8]);
          a = __builtin_amdgcn_mfma_f32_16x16x32_bf16(kf, qf[ks], a, 0, 0, 0);
        }
        sv[kt] = a;
      }
      __builtin_amdgcn_s_setprio(0);

      // causal mask (last tile only) + tile max
      const bool lastt = (t == nt - 1);
      float tmax = -INFINITY;
#pragma unroll
      for (int kt = 0; kt < 4; ++kt)
#pragma unroll
        for (int r = 0; r < 4; ++r) {
          float v = sv[kt][r];
          if (lastt) {
            const int key = t * 64 + kt * 16 + g * 4 + r;
            if (key > qw0 + lo) v = -INFINITY;
          }
          sv[kt][r] = v;
          tmax = fmaxf(tmax, v);
        }
      tmax = fmaxf(tmax, __shfl_xor(tmax, 16));
      tmax = fmaxf(tmax, __shfl_xor(tmax, 32));

      // defer-max (T13): only rescale when the running max grew by > 8 (log2 domain)
      if (!__all(tmax <= m + 8.f)) {
        const float mn   = fmaxf(m, tmax);
        const float corr = exp2f(m - mn);
        l *= corr;
#pragma unroll
        for (int dt = 0; dt < 4; ++dt)
#pragma unroll
          for (int r = 0; r < 4; ++r) oacc[dt][r] *= corr;
        m = mn;
      }

      float ps = 0.f;
      s16x4 pb[4];
#pragma unroll
      for (int kt = 0; kt < 4; ++kt)
#pragma unroll
        for (int r = 0; r < 4; ++r) {
          const float p = exp2f(sv[kt][r] - m);   // bounded by 2^8 when deferred
          ps += p;
          pb[kt][r] = (short)f2bf(p);
        }
      ps += __shfl_xor(ps, 16);
      ps += __shfl_xor(ps, 32);
      l += ps;

      // PV: O^T[d][q] += sum_key Vt[d][key] * P^T[key][q]  (16x16x16, k = g*4+j)
      __builtin_amdgcn_s_setprio(1);
#pragma unroll
      for (int dt = 0; dt < 4; ++dt) {
        const int dl = dt * 16 + lo;
#pragma unroll
        for (int kt = 0; kt < 4; ++kt) {
          const int ck  = 2 * kt + (g >> 1);
          const int off = dl * 64 + ((ck ^ (dl & 7)) * 8) + (g & 1) * 4;
          s16x4 vf = *reinterpret_cast<const s16x4*>(&Vl[cur][off]);
          oacc[dt] = __builtin_amdgcn_mfma_f32_16x16x16bf16_1k(vf, pb[kt], oacc[dt], 0, 0, 0);
        }
      }
      __builtin_amdgcn_s_setprio(0);

      __syncthreads();
      cur ^= 1;
    }

    // epilogue: lane's q = qw0+lo; oacc[dt] rows = d = dt*16 + g*4 + r  (bf16 out)
    const float inv = 1.f / l;
    const int s = qw0 + lo;
#pragma unroll
    for (int dt = 0; dt < 4; ++dt) {
      u16x4 pk;
#pragma unroll
      for (int r = 0; r < 4; ++r) pk[r] = f2bf(oacc[dt][r] * inv);
      *reinterpret_cast<u16x4*>(&O[((size_t)(b * 2048 + s)) * 1024 + h * 64 + dt * 16 + g * 4]) = pk;
    }
  };

  run(31 - (int)blockIdx.x);   // big half first
  run((int)blockIdx.x);
}

// ---------- launch ----------

extern "C" void kernel_launch(void* const* d_in, const int* in_sizes, int n_in,
                              void* d_out, int out_size, void* d_ws, size_t ws_size,
                              hipStream_t stream) {
  const float* x  = (const float*)d_in[0];
  const float* Wq = (const float*)d_in[1];
  const float* Wk = (const float*)d_in[2];
  const float* Wv = (const float*)d_in[3];
  const float* Wo = (const float*)d_in[4];
  float* out = (float*)d_out;

  char* ws = (char*)d_ws;
  const size_t MiB = 1024 * 1024;
  unsigned short* x_bf = (unsigned short*)(ws);              // 8 MiB (aliased by a_s)
  unsigned short* a_s  = (unsigned short*)(ws);              // 8 MiB bf16 attn out
  unsigned short* w_bf = (unsigned short*)(ws + 8  * MiB);   // 4 x 2 MiB
  unsigned short* q_s  = (unsigned short*)(ws + 16 * MiB);   // 8 MiB
  unsigned short* k_s  = (unsigned short*)(ws + 24 * MiB);   // 8 MiB
  unsigned short* vt_s = (unsigned short*)(ws + 32 * MiB);   // 8 MiB

  dim3 blk(256);
  cvt_inputs<<<2048, blk, 0, stream>>>(x, Wq, Wk, Wv, Wo, x_bf, w_bf);
  gemm_qkv<<<dim3(8, 32, 3), blk, 0, stream>>>(x_bf, w_bf, q_s, k_s, vt_s);
  attn_fwd<<<dim3(16, 32, 1), blk, 0, stream>>>(q_s, k_s, vt_s, a_s);
  gemm_out<<<dim3(8, 32, 1), blk, 0, stream>>>(a_s, w_bf, out);
}